// Round 1
// baseline (211.272 us; speedup 1.0000x reference)
//
#include <hip/hip_runtime.h>
#include <hip/hip_bf16.h>

// Fused: inference-BN + ReLU + 2x2 avgpool (moved before the 1x1 conv by
// linearity) + 1x1 conv as bf16 MFMA GEMM.
//   pooled M = 16*28*28 = 12544, K = 512, N = 256
// One block = 32 pooled pixels x all 256 outputs -> x read exactly once.

typedef __attribute__((ext_vector_type(8))) short bf16x8;   // 8 bf16 (4 VGPRs)
typedef __attribute__((ext_vector_type(4))) short bf16x4;
typedef __attribute__((ext_vector_type(4))) float f32x4;

constexpr int BB   = 16;
constexpr int CIN  = 512;
constexpr int COUT = 256;
constexpr int HH   = 56;
constexpr int WW   = 56;
constexpr int HP   = 28;
constexpr int WP   = 28;
constexpr int MT   = 32;    // pooled pixels per block (12544 = 392*32)
constexpr int KC   = 64;    // K-chunk
constexpr int LDK  = 72;    // LDS row stride in bf16 (144 B, 16B-aligned rows)

__device__ __forceinline__ short f2bf(float f) {
    __hip_bfloat16 h = __float2bfloat16(f);
    return *reinterpret_cast<short*>(&h);
}

__global__ __launch_bounds__(256)
void fused_bn_relu_conv_pool(const float* __restrict__ x,
                             const float* __restrict__ bnw,
                             const float* __restrict__ bnb,
                             const float* __restrict__ bnm,
                             const float* __restrict__ bnv,
                             const float* __restrict__ w,
                             float* __restrict__ out)
{
    __shared__ __align__(16) short Alds[MT * LDK];     // pooled pixels [m][k]
    __shared__ __align__(16) short Blds[COUT * LDK];   // weights [o][k]
    __shared__ float s_s[CIN];
    __shared__ float s_t[CIN];

    const int tid = threadIdx.x;

    // Per-channel BN affine: y = x*s + t
    for (int c = tid; c < CIN; c += 256) {
        float inv = rsqrtf(bnv[c] + 1e-5f);
        float s = bnw[c] * inv;
        s_s[c] = s;
        s_t[c] = bnb[c] - bnm[c] * s;
    }

    // staging geometry: thread -> (pooled pixel mloc, channel group cg)
    const int mloc = tid & (MT - 1);      // 0..31
    const int cg   = tid >> 5;            // 0..7, 8 channels each
    const int m    = blockIdx.x * MT + mloc;
    const int b    = m / (HP * WP);
    const int r    = m % (HP * WP);
    const int hp   = r / WP;
    const int wp   = r % WP;
    const float2* xr0 = reinterpret_cast<const float2*>(
        x + (size_t)b * CIN * HH * WW + (size_t)(2 * hp) * WW + 2 * wp);
    const float2* xr1 = xr0 + WW / 2;     // next raw row

    const int lane = tid & 63;
    const int wv   = tid >> 6;            // wave 0..3 -> o-range wv*64
    const int l16  = lane & 15;
    const int q    = lane >> 4;

    f32x4 acc[4][2];                      // [n-subtile][m-subtile]
    #pragma unroll
    for (int i = 0; i < 4; i++)
        #pragma unroll
        for (int j = 0; j < 2; j++)
            acc[i][j] = (f32x4){0.f, 0.f, 0.f, 0.f};

    __syncthreads();                      // s_s / s_t ready

    for (int kc = 0; kc < CIN; kc += KC) {
        // ---- stage A: x -> BN -> ReLU -> 2x2 pool -> bf16 LDS [32][72] ----
        // preload all 16 float2 first (keeps 16 loads in flight per lane)
        float2 va[8], vb[8];
        #pragma unroll
        for (int j = 0; j < 8; j++) {
            const int c = kc + cg * 8 + j;
            va[j] = xr0[(size_t)c * (HH * WW / 2)];
            vb[j] = xr1[(size_t)c * (HH * WW / 2)];
        }
        bf16x8 apack;
        #pragma unroll
        for (int j = 0; j < 8; j++) {
            const int c = kc + cg * 8 + j;
            const float s = s_s[c], t = s_t[c];
            float y0 = fmaxf(fmaf(va[j].x, s, t), 0.f);
            float y1 = fmaxf(fmaf(va[j].y, s, t), 0.f);
            float y2 = fmaxf(fmaf(vb[j].x, s, t), 0.f);
            float y3 = fmaxf(fmaf(vb[j].y, s, t), 0.f);
            apack[j] = f2bf((y0 + y1 + y2 + y3) * 0.25f);
        }
        *reinterpret_cast<bf16x8*>(&Alds[mloc * LDK + cg * 8]) = apack;

        // ---- stage B: weight fp32 -> bf16 LDS [256][72] ----
        {
            const int kq = tid & 15;      // float4 index within 64-float row seg
            const int og = tid >> 4;      // 0..15
            #pragma unroll
            for (int it = 0; it < 16; it++) {
                const int o = it * 16 + og;
                float4 wvv = *reinterpret_cast<const float4*>(
                    w + (size_t)o * CIN + kc + kq * 4);
                bf16x4 bp;
                bp[0] = f2bf(wvv.x);
                bp[1] = f2bf(wvv.y);
                bp[2] = f2bf(wvv.z);
                bp[3] = f2bf(wvv.w);
                *reinterpret_cast<bf16x4*>(&Blds[o * LDK + kq * 4]) = bp;
            }
        }
        __syncthreads();

        // ---- MFMA: D[o][m] += W[o][k] * Y[m][k] ----
        #pragma unroll
        for (int kh = 0; kh < 2; kh++) {
            bf16x8 bfrag[2];
            #pragma unroll
            for (int ms = 0; ms < 2; ms++)
                bfrag[ms] = *reinterpret_cast<const bf16x8*>(
                    &Alds[(ms * 16 + l16) * LDK + kh * 32 + q * 8]);
            #pragma unroll
            for (int ns = 0; ns < 4; ns++) {
                bf16x8 afrag = *reinterpret_cast<const bf16x8*>(
                    &Blds[(wv * 64 + ns * 16 + l16) * LDK + kh * 32 + q * 8]);
                acc[ns][0] = __builtin_amdgcn_mfma_f32_16x16x32_bf16(
                    afrag, bfrag[0], acc[ns][0], 0, 0, 0);
                acc[ns][1] = __builtin_amdgcn_mfma_f32_16x16x32_bf16(
                    afrag, bfrag[1], acc[ns][1], 0, 0, 0);
            }
        }
        __syncthreads();                  // protect LDS for next chunk
    }

    // ---- epilogue: D col = m (lane&15) -> m-contiguous coalesced stores ----
    // out flat = b*COUT*784 + o*784 + (hp*28+wp), and (hp*28+wp) = m % 784
    int addrm[2];
    #pragma unroll
    for (int ms = 0; ms < 2; ms++) {
        int mm = blockIdx.x * MT + ms * 16 + l16;
        int bb = mm / (HP * WP);
        int rr = mm % (HP * WP);
        addrm[ms] = bb * (COUT * HP * WP) + rr;
    }
    #pragma unroll
    for (int ns = 0; ns < 4; ns++)
        #pragma unroll
        for (int ms = 0; ms < 2; ms++)
            #pragma unroll
            for (int rg = 0; rg < 4; rg++) {
                const int o = wv * 64 + ns * 16 + q * 4 + rg;
                out[(size_t)addrm[ms] + (size_t)o * (HP * WP)] = acc[ns][ms][rg];
            }
}

extern "C" void kernel_launch(void* const* d_in, const int* in_sizes, int n_in,
                              void* d_out, int out_size, void* d_ws, size_t ws_size,
                              hipStream_t stream) {
    const float* x   = (const float*)d_in[0];
    const float* bnw = (const float*)d_in[1];
    const float* bnb = (const float*)d_in[2];
    const float* bnm = (const float*)d_in[3];
    const float* bnv = (const float*)d_in[4];
    const float* w   = (const float*)d_in[5];
    float* out = (float*)d_out;

    const int grid = (BB * HP * WP) / MT;   // 392
    fused_bn_relu_conv_pool<<<grid, 256, 0, stream>>>(x, bnw, bnb, bnm, bnv, w, out);
}

// Round 2
// 187.701 us; speedup vs baseline: 1.1256x; 1.1256x over previous
//
#include <hip/hip_runtime.h>
#include <hip/hip_bf16.h>

// Fused: BN(inference)+ReLU+2x2 avgpool (hoisted before conv by linearity)
// + 1x1 conv as bf16 MFMA GEMM.  pooled M=12544, K=512, N=256.
// R2: MT=16 (784 blocks), W pre-converted to bf16 in d_ws and loaded as MFMA
// fragments directly from global (L2-resident) — no B-tile LDS stage.
// x-loads register-double-buffered across the fully-unrolled K-loop.

typedef short bf16x8 __attribute__((ext_vector_type(8)));
typedef short bf16x4 __attribute__((ext_vector_type(4)));
typedef float f32x4  __attribute__((ext_vector_type(4)));

constexpr int BB=16, CIN=512, COUT=256, HH=56, WW=56, HP=28, WP=28;
constexpr int MT  = 16;          // pooled pixels per block (12544 = 784*16)
constexpr int KC  = 64;          // K-chunk
constexpr int LDK = 72;          // LDS row stride (bf16), keeps 16B alignment
constexpr int NCHUNK = CIN / KC; // 8

__device__ __forceinline__ short f2bf(float f) {
    __hip_bfloat16 h = __float2bfloat16(f);
    return *reinterpret_cast<short*>(&h);
}

__global__ __launch_bounds__(256)
void convert_w_kernel(const float* __restrict__ w, short* __restrict__ wb) {
    int i = blockIdx.x * 256 + threadIdx.x;      // 32768 threads, 4 elems each
    float4 v = reinterpret_cast<const float4*>(w)[i];
    bf16x4 o;
    o[0] = f2bf(v.x); o[1] = f2bf(v.y); o[2] = f2bf(v.z); o[3] = f2bf(v.w);
    reinterpret_cast<bf16x4*>(wb)[i] = o;
}

__global__ __launch_bounds__(256)
void fused_main(const float* __restrict__ x,  const float* __restrict__ bnw,
                const float* __restrict__ bnb, const float* __restrict__ bnm,
                const float* __restrict__ bnv, const short* __restrict__ wb,
                float* __restrict__ out)
{
    __shared__ __align__(16) short Alds[MT * LDK];   // 2.3 KB
    __shared__ float s_s[CIN];
    __shared__ float s_t[CIN];

    const int tid = threadIdx.x;

    for (int c = tid; c < CIN; c += 256) {
        float inv = rsqrtf(bnv[c] + 1e-5f);
        float s = bnw[c] * inv;
        s_s[c] = s;
        s_t[c] = bnb[c] - bnm[c] * s;
    }

    // staging geometry: mloc = pooled pixel (== lane&15), cg = 4-channel group
    const int mloc = tid & (MT - 1);
    const int cg   = tid >> 4;                  // 0..15
    const int m    = blockIdx.x * MT + mloc;
    const int b    = m / (HP * WP);
    const int r    = m % (HP * WP);
    const int hp   = r / WP;
    const int wp   = r % WP;
    const float2* xr0 = reinterpret_cast<const float2*>(
        x + (size_t)b * CIN * HH * WW + (size_t)(2 * hp) * WW + 2 * wp);
    const float2* xr1 = xr0 + WW / 2;

    const int lane = tid & 63;
    const int wv   = tid >> 6;                  // wave -> 64 outputs
    const int l16  = lane & 15;                 // == mloc
    const int q    = lane >> 4;

    f32x4 acc[4];
    #pragma unroll
    for (int i = 0; i < 4; i++) acc[i] = (f32x4){0.f, 0.f, 0.f, 0.f};

    // W fragment base for this lane: row o = wv*64 + ns*16 + l16, col q*8
    const short* wbase = wb + ((size_t)(wv * 64 + l16)) * CIN + q * 8;

    // double-buffered x registers
    float2 va[2][4], vb[2][4];
    #pragma unroll
    for (int j = 0; j < 4; j++) {
        int c = cg * 4 + j;
        va[0][j] = xr0[(size_t)c * (HH * WW / 2)];
        vb[0][j] = xr1[(size_t)c * (HH * WW / 2)];
    }
    __syncthreads();                            // s_s/s_t ready

    #pragma unroll
    for (int ck = 0; ck < NCHUNK; ck++) {
        const int kc  = ck * KC;
        const int cur = ck & 1;
        const int nxt = cur ^ 1;

        // BN + ReLU + pool -> bf16 -> Alds
        bf16x4 apack;
        #pragma unroll
        for (int j = 0; j < 4; j++) {
            int c = kc + cg * 4 + j;
            float s = s_s[c], t = s_t[c];
            float y0 = fmaxf(fmaf(va[cur][j].x, s, t), 0.f);
            float y1 = fmaxf(fmaf(va[cur][j].y, s, t), 0.f);
            float y2 = fmaxf(fmaf(vb[cur][j].x, s, t), 0.f);
            float y3 = fmaxf(fmaf(vb[cur][j].y, s, t), 0.f);
            apack[j] = f2bf((y0 + y1 + y2 + y3) * 0.25f);
        }
        *reinterpret_cast<bf16x4*>(&Alds[mloc * LDK + cg * 4]) = apack;
        __syncthreads();

        // W fragments for this chunk (L2-resident bf16), issued first
        bf16x8 wfrag[2][4];
        #pragma unroll
        for (int kh = 0; kh < 2; kh++)
            #pragma unroll
            for (int ns = 0; ns < 4; ns++)
                wfrag[kh][ns] = *reinterpret_cast<const bf16x8*>(
                    wbase + (size_t)ns * 16 * CIN + kc + kh * 32);

        // prefetch next chunk's x AFTER the W loads (vmcnt FIFO: the MFMA's
        // W-wait becomes vmcnt(8), leaving the HBM prefetch in flight)
        if (ck < NCHUNK - 1) {
            #pragma unroll
            for (int j = 0; j < 4; j++) {
                int c = kc + KC + cg * 4 + j;
                va[nxt][j] = xr0[(size_t)c * (HH * WW / 2)];
                vb[nxt][j] = xr1[(size_t)c * (HH * WW / 2)];
            }
        }

        // MFMA: D[o][m] += W[o][k] * Y[m][k]
        #pragma unroll
        for (int kh = 0; kh < 2; kh++) {
            bf16x8 bfrag = *reinterpret_cast<const bf16x8*>(
                &Alds[l16 * LDK + kh * 32 + q * 8]);
            #pragma unroll
            for (int ns = 0; ns < 4; ns++)
                acc[ns] = __builtin_amdgcn_mfma_f32_16x16x32_bf16(
                    wfrag[kh][ns], bfrag, acc[ns], 0, 0, 0);
        }
        __syncthreads();                        // protect Alds for next chunk
    }

    // epilogue: D col = m = l16 (== mloc, so b/r already computed)
    const int addrm = b * (COUT * HP * WP) + r;
    #pragma unroll
    for (int ns = 0; ns < 4; ns++)
        #pragma unroll
        for (int rg = 0; rg < 4; rg++) {
            int o = wv * 64 + ns * 16 + q * 4 + rg;
            out[(size_t)addrm + (size_t)o * (HP * WP)] = acc[ns][rg];
        }
}

extern "C" void kernel_launch(void* const* d_in, const int* in_sizes, int n_in,
                              void* d_out, int out_size, void* d_ws, size_t ws_size,
                              hipStream_t stream) {
    const float* x   = (const float*)d_in[0];
    const float* bnw = (const float*)d_in[1];
    const float* bnb = (const float*)d_in[2];
    const float* bnm = (const float*)d_in[3];
    const float* bnv = (const float*)d_in[4];
    const float* w   = (const float*)d_in[5];
    float* out = (float*)d_out;
    short* wb  = (short*)d_ws;                  // 256 KB bf16 weights

    convert_w_kernel<<<(COUT * CIN / 4) / 256, 256, 0, stream>>>(w, wb);

    const int grid = (BB * HP * WP) / MT;       // 784
    fused_main<<<grid, 256, 0, stream>>>(x, bnw, bnb, bnm, bnv, wb, out);
}

// Round 3
// 174.505 us; speedup vs baseline: 1.2107x; 1.0756x over previous
//
#include <hip/hip_runtime.h>
#include <hip/hip_bf16.h>

// Fused: BN(inference)+ReLU+2x2 avgpool (hoisted before conv by linearity)
// + 1x1 conv as bf16 MFMA GEMM.  pooled M=12544, K=512, N=256.
// R3: W pre-swizzled into MFMA fragment order (coalesced 1KB fragment loads,
// was a 64-line gather per instr), x prefetch distance 2, single barrier per
// K-chunk via double-buffered A-tile LDS.

typedef short bf16x8 __attribute__((ext_vector_type(8)));
typedef short bf16x4 __attribute__((ext_vector_type(4)));
typedef float f32x4  __attribute__((ext_vector_type(4)));

constexpr int BB=16, CIN=512, COUT=256, HH=56, WW=56, HP=28, WP=28;
constexpr int MT  = 16;          // pooled pixels per block (12544 = 784*16)
constexpr int KC  = 64;          // K-chunk
constexpr int LDK = 72;          // LDS row stride (bf16), 16B-aligned rows
constexpr int NCHUNK = CIN / KC; // 8

__device__ __forceinline__ short f2bf(float f) {
    __hip_bfloat16 h = __float2bfloat16(f);
    return *reinterpret_cast<short*>(&h);
}

// Swizzle W into MFMA A-fragment order:
//   wsw[((ot*16+ksg)*64 + lane)*8 + j] = W[ot*16+(lane&15)][ksg*32+(lane>>4)*8+j]
// so a wave's fragment load is lane*16B contiguous (one 1KB coalesced instr).
__global__ __launch_bounds__(256)
void convert_w(const float* __restrict__ w, short* __restrict__ wsw) {
    int t    = blockIdx.x * 256 + threadIdx.x;   // [0, 16384)
    int lane = t & 63;
    int tile = t >> 6;                           // ot*16 + ksg
    int ot   = tile >> 4, ksg = tile & 15;
    int o    = ot * 16 + (lane & 15);
    int k    = ksg * 32 + (lane >> 4) * 8;
    const float4* src = reinterpret_cast<const float4*>(w + (size_t)o * CIN + k);
    float4 v0 = src[0], v1 = src[1];
    bf16x8 p;
    p[0]=f2bf(v0.x); p[1]=f2bf(v0.y); p[2]=f2bf(v0.z); p[3]=f2bf(v0.w);
    p[4]=f2bf(v1.x); p[5]=f2bf(v1.y); p[6]=f2bf(v1.z); p[7]=f2bf(v1.w);
    reinterpret_cast<bf16x8*>(wsw)[t] = p;
}

__global__ __launch_bounds__(256)
void fused_main(const float* __restrict__ x,  const float* __restrict__ bnw,
                const float* __restrict__ bnb, const float* __restrict__ bnm,
                const float* __restrict__ bnv, const short* __restrict__ wsw,
                float* __restrict__ out)
{
    __shared__ __align__(16) short Alds[2][MT * LDK];   // double-buffered, 4.6 KB
    __shared__ float s_s[CIN];
    __shared__ float s_t[CIN];

    const int tid = threadIdx.x;

    for (int c = tid; c < CIN; c += 256) {
        float inv = rsqrtf(bnv[c] + 1e-5f);
        float s = bnw[c] * inv;
        s_s[c] = s;
        s_t[c] = bnb[c] - bnm[c] * s;
    }

    // staging geometry: mloc = pooled pixel (== lane&15), cg = 4-channel group
    const int mloc = tid & (MT - 1);
    const int cg   = tid >> 4;                  // 0..15
    const int m    = blockIdx.x * MT + mloc;
    const int b    = m / (HP * WP);
    const int r    = m % (HP * WP);
    const int hp   = r / WP;
    const int wp   = r % WP;
    const float2* xr0 = reinterpret_cast<const float2*>(
        x + (size_t)b * CIN * HH * WW + (size_t)(2 * hp) * WW + 2 * wp);
    const float2* xr1 = xr0 + WW / 2;

    const int lane = tid & 63;
    const int wv   = tid >> 6;                  // wave -> 64 outputs
    const int l16  = lane & 15;                 // == mloc
    const int q    = lane >> 4;

    f32x4 acc[4];
    #pragma unroll
    for (int i = 0; i < 4; i++) acc[i] = (f32x4){0.f, 0.f, 0.f, 0.f};

    // swizzled-W fragment pointer: index = (ot*16 + ksg)*64 + lane
    const bf16x8* wfp = reinterpret_cast<const bf16x8*>(wsw);

    // x register buffers, prefetch distance 2
    float2 va[2][4], vb[2][4];
    #pragma unroll
    for (int pk = 0; pk < 2; pk++)
        #pragma unroll
        for (int j = 0; j < 4; j++) {
            int c = pk * KC + cg * 4 + j;
            va[pk][j] = xr0[(size_t)c * (HH * WW / 2)];
            vb[pk][j] = xr1[(size_t)c * (HH * WW / 2)];
        }
    __syncthreads();                            // s_s/s_t ready

    #pragma unroll
    for (int ck = 0; ck < NCHUNK; ck++) {
        const int kc  = ck * KC;
        const int buf = ck & 1;

        // BN + ReLU + pool -> bf16 -> Alds[buf]
        bf16x4 apack;
        #pragma unroll
        for (int j = 0; j < 4; j++) {
            int c = kc + cg * 4 + j;
            float s = s_s[c], t = s_t[c];
            float y0 = fmaxf(fmaf(va[buf][j].x, s, t), 0.f);
            float y1 = fmaxf(fmaf(va[buf][j].y, s, t), 0.f);
            float y2 = fmaxf(fmaf(vb[buf][j].x, s, t), 0.f);
            float y3 = fmaxf(fmaf(vb[buf][j].y, s, t), 0.f);
            apack[j] = f2bf((y0 + y1 + y2 + y3) * 0.25f);
        }
        *reinterpret_cast<bf16x4*>(&Alds[buf][mloc * LDK + cg * 4]) = apack;

        // W fragments (coalesced, L2-resident) — issued before the barrier
        bf16x8 wfrag[2][4];
        #pragma unroll
        for (int kh = 0; kh < 2; kh++)
            #pragma unroll
            for (int ns = 0; ns < 4; ns++) {
                int ot  = wv * 4 + ns;
                int ksg = ck * 2 + kh;
                wfrag[kh][ns] = wfp[(ot * 16 + ksg) * 64 + lane];
            }

        // prefetch x for chunk ck+2 into the buffer BN just consumed
        if (ck < NCHUNK - 2) {
            #pragma unroll
            for (int j = 0; j < 4; j++) {
                int c = kc + 2 * KC + cg * 4 + j;
                va[buf][j] = xr0[(size_t)c * (HH * WW / 2)];
                vb[buf][j] = xr1[(size_t)c * (HH * WW / 2)];
            }
        }

        __syncthreads();                        // Alds[buf] ready (sole barrier)

        // MFMA: D[o][m] += W[o][k] * Y[m][k]
        #pragma unroll
        for (int kh = 0; kh < 2; kh++) {
            bf16x8 bfrag = *reinterpret_cast<const bf16x8*>(
                &Alds[buf][l16 * LDK + kh * 32 + q * 8]);
            #pragma unroll
            for (int ns = 0; ns < 4; ns++)
                acc[ns] = __builtin_amdgcn_mfma_f32_16x16x32_bf16(
                    wfrag[kh][ns], bfrag, acc[ns], 0, 0, 0);
        }
        // no trailing barrier: next chunk writes the other Alds buffer; the
        // per-chunk barrier orders reads(buf, ck) before writes(buf, ck+2).
    }

    // epilogue: D col = m = l16 (== mloc, so b/r already computed)
    const int addrm = b * (COUT * HP * WP) + r;
    #pragma unroll
    for (int ns = 0; ns < 4; ns++)
        #pragma unroll
        for (int rg = 0; rg < 4; rg++) {
            int o = wv * 64 + ns * 16 + q * 4 + rg;
            out[(size_t)addrm + (size_t)o * (HP * WP)] = acc[ns][rg];
        }
}

extern "C" void kernel_launch(void* const* d_in, const int* in_sizes, int n_in,
                              void* d_out, int out_size, void* d_ws, size_t ws_size,
                              hipStream_t stream) {
    const float* x   = (const float*)d_in[0];
    const float* bnw = (const float*)d_in[1];
    const float* bnb = (const float*)d_in[2];
    const float* bnm = (const float*)d_in[3];
    const float* bnv = (const float*)d_in[4];
    const float* w   = (const float*)d_in[5];
    float* out = (float*)d_out;
    short* wsw = (short*)d_ws;                  // 256 KB swizzled bf16 weights

    convert_w<<<(COUT * CIN / 8) / 256, 256, 0, stream>>>(w, wsw);

    const int grid = (BB * HP * WP) / MT;       // 784
    fused_main<<<grid, 256, 0, stream>>>(x, bnw, bnb, bnm, bnv, wsw, out);
}

// Round 4
// 173.425 us; speedup vs baseline: 1.2182x; 1.0062x over previous
//
#include <hip/hip_runtime.h>
#include <hip/hip_bf16.h>

// R4: decoupled two-stage.
//  stage1: x --BN+ReLU+2x2pool--> bf16 y, stored in MFMA-fragment order in
//          d_ws (pure HBM stream, no barriers in the hot path, 3136 blocks);
//          64 extra blocks swizzle W fp32->bf16 fragment order.
//  stage2: fragment-order GEMM y[12544x512] x W[256x512]^T -> out.
//          No LDS, no barriers: all operands are coalesced 1KB fragment loads.

typedef short bf16x8 __attribute__((ext_vector_type(8)));
typedef float f32x4  __attribute__((ext_vector_type(4)));

constexpr int BB=16, CIN=512, COUT=256, HH=56, WW=56, HP=28, WP=28;
constexpr int MTILES  = (BB * HP * WP) / 16;   // 784 m-tiles of 16 pooled pixels
constexpr int XBLOCKS = MTILES * 4;            // 3136: each block = 1 mt x 128 chans
constexpr int WBLOCKS = (COUT * CIN / 8) / 256; // 64 W-swizzle blocks

__device__ __forceinline__ short f2bf(float f) {
    __hip_bfloat16 h = __float2bfloat16(f);
    return *reinterpret_cast<short*>(&h);
}

// Fragment-order layouts (both consumed by stage2, verified vs R2/R3 kernel):
//   wsw[(ot*16+ksg)*64 + lane] : W[o=ot*16+(lane&15)][k=ksg*32+(lane>>4)*8 + j]
//   ysw[(mt*16+ksg)*64 + lane] : y[m=mt*16+(lane&15)][k=ksg*32+(lane>>4)*8 + j]

__global__ __launch_bounds__(256)
void stage1(const float* __restrict__ x,  const float* __restrict__ bnw,
            const float* __restrict__ bnb, const float* __restrict__ bnm,
            const float* __restrict__ bnv, const float* __restrict__ w,
            short* __restrict__ ysw, short* __restrict__ wsw)
{
    const int blk = blockIdx.x;
    const int tid = threadIdx.x;

    if (blk >= XBLOCKS) {
        // ---- W swizzle path (64 blocks) ----
        int t    = (blk - XBLOCKS) * 256 + tid;      // [0, 16384)
        int lane = t & 63;
        int tile = t >> 6;                           // ot*16 + ksg
        int o    = (tile >> 4) * 16 + (lane & 15);
        int k    = (tile & 15) * 32 + (lane >> 4) * 8;
        const float4* src = reinterpret_cast<const float4*>(w + (size_t)o * CIN + k);
        float4 v0 = src[0], v1 = src[1];
        bf16x8 p;
        p[0]=f2bf(v0.x); p[1]=f2bf(v0.y); p[2]=f2bf(v0.z); p[3]=f2bf(v0.w);
        p[4]=f2bf(v1.x); p[5]=f2bf(v1.y); p[6]=f2bf(v1.z); p[7]=f2bf(v1.w);
        reinterpret_cast<bf16x8*>(wsw)[t] = p;
        return;
    }

    // ---- x streaming path: block = (mt, quarter of channels) ----
    __shared__ float s_s[128];
    __shared__ float s_t[128];

    const int kblk = blk & 3;            // channel quarter: c in [kblk*128, +128)
    const int mt   = blk >> 2;

    if (tid < 128) {
        int c = kblk * 128 + tid;
        float inv = rsqrtf(bnv[c] + 1e-5f);
        float s = bnw[c] * inv;
        s_s[tid] = s;
        s_t[tid] = bnb[c] - bnm[c] * s;
    }
    __syncthreads();

    const int l16 = tid & 15;            // pooled pixel within tile
    const int k8l = tid >> 4;            // local 8-channel group, 0..15
    const int k8  = kblk * 16 + k8l;     // global 8-channel group, 0..63

    const int m  = mt * 16 + l16;
    const int b  = m / (HP * WP);
    const int r  = m % (HP * WP);
    const int hp = r / WP;
    const int wp = r % WP;
    const float2* xr0 = reinterpret_cast<const float2*>(
        x + (size_t)b * CIN * HH * WW + (size_t)(2 * hp) * WW + 2 * wp);
    const float2* xr1 = xr0 + WW / 2;

    // issue all 16 loads before any use (max MLP)
    const int cb = k8 * 8;
    float2 va[8], vb[8];
    #pragma unroll
    for (int j = 0; j < 8; j++) {
        va[j] = xr0[(size_t)(cb + j) * (HH * WW / 2)];
        vb[j] = xr1[(size_t)(cb + j) * (HH * WW / 2)];
    }

    bf16x8 p;
    #pragma unroll
    for (int j = 0; j < 8; j++) {
        int cl = k8l * 8 + j;
        float s = s_s[cl], t = s_t[cl];
        float y0 = fmaxf(fmaf(va[j].x, s, t), 0.f);
        float y1 = fmaxf(fmaf(va[j].y, s, t), 0.f);
        float y2 = fmaxf(fmaf(vb[j].x, s, t), 0.f);
        float y3 = fmaxf(fmaf(vb[j].y, s, t), 0.f);
        p[j] = f2bf((y0 + y1 + y2 + y3) * 0.25f);
    }

    // fragment-order store: lane = (k8&3)*16 + l16, ksg = k8>>2
    // consecutive tid -> consecutive 16B slots -> 4KB contiguous per wave-group
    int idx8 = (mt * 16 + (k8 >> 2)) * 64 + (k8 & 3) * 16 + l16;
    reinterpret_cast<bf16x8*>(ysw)[idx8] = p;
}

__global__ __launch_bounds__(256)
void stage2(const short* __restrict__ ysw, const short* __restrict__ wsw,
            float* __restrict__ out)
{
    const int mt   = blockIdx.x;         // 0..783
    const int tid  = threadIdx.x;
    const int lane = tid & 63;
    const int wv   = tid >> 6;           // wave -> 64 outputs
    const int l16  = lane & 15;
    const int q    = lane >> 4;

    const bf16x8* yfp = reinterpret_cast<const bf16x8*>(ysw);
    const bf16x8* wfp = reinterpret_cast<const bf16x8*>(wsw);

    f32x4 acc[4];
    #pragma unroll
    for (int i = 0; i < 4; i++) acc[i] = (f32x4){0.f, 0.f, 0.f, 0.f};

    #pragma unroll
    for (int ksg = 0; ksg < 16; ksg++) {
        bf16x8 yf = yfp[(mt * 16 + ksg) * 64 + lane];
        #pragma unroll
        for (int ns = 0; ns < 4; ns++) {
            bf16x8 wf = wfp[((wv * 4 + ns) * 16 + ksg) * 64 + lane];
            acc[ns] = __builtin_amdgcn_mfma_f32_16x16x32_bf16(wf, yf, acc[ns], 0, 0, 0);
        }
    }

    // epilogue: D col = m = l16 -> m-contiguous stores
    const int m = mt * 16 + l16;
    const int b = m / (HP * WP);
    const int r = m % (HP * WP);
    const int addrm = b * (COUT * HP * WP) + r;
    #pragma unroll
    for (int ns = 0; ns < 4; ns++)
        #pragma unroll
        for (int rg = 0; rg < 4; rg++) {
            int o = wv * 64 + ns * 16 + q * 4 + rg;
            out[(size_t)addrm + (size_t)o * (HP * WP)] = acc[ns][rg];
        }
}

extern "C" void kernel_launch(void* const* d_in, const int* in_sizes, int n_in,
                              void* d_out, int out_size, void* d_ws, size_t ws_size,
                              hipStream_t stream) {
    const float* x   = (const float*)d_in[0];
    const float* bnw = (const float*)d_in[1];
    const float* bnb = (const float*)d_in[2];
    const float* bnm = (const float*)d_in[3];
    const float* bnv = (const float*)d_in[4];
    const float* w   = (const float*)d_in[5];
    float* out = (float*)d_out;

    short* wsw = (short*)d_ws;                         // 256 KB
    short* ysw = (short*)d_ws + (size_t)COUT * CIN;    // 12.8 MB

    stage1<<<XBLOCKS + WBLOCKS, 256, 0, stream>>>(x, bnw, bnb, bnm, bnv, w, ysw, wsw);
    stage2<<<MTILES, 256, 0, stream>>>(ysw, wsw, out);
}